// Round 1
// 54.965 us; speedup vs baseline: 1.2130x; 1.2130x over previous
//
#include <hip/hip_runtime.h>
#include <hip/hip_fp16.h>

#define DIM 128
#define GROWS 32

typedef _Float16 f16x8 __attribute__((ext_vector_type(8)));
typedef float f32x4 __attribute__((ext_vector_type(4)));

// ---------- Kernel 1 (fused): table transform embW = fp16(emb @ W) via
// fp16 MFMA (memory-bound: same 76.8MB traffic as the old fp32->fp16
// convert, GEMM rides free on the matrix pipe) + segment-boundary scan in
// the same launch (independent work, separate block range; transform
// blocks first so the long-running blocks start immediately).
//
// MFMA fragment layouts (mfma_f32_16x16x32_f16, m89/m91-verified conv.):
//   A (16x32): row = lane&15, k = (lane>>4)*8 + i  -> 8 contiguous floats
//   B (32x16): col = lane&15, k = (lane>>4)*8 + i  -> stride-DIM scalars
//   D (16x16): col = lane&15, row = (lane>>4)*4 + reg
// All 32 B-fragments (8 ntiles x 4 ksteps = 128 VGPRs) preloaded once per
// wave, reused across grid-strided M-tiles.
__global__ __launch_bounds__(256, 2) void prep_kernel(
    const int* __restrict__ segs, int* __restrict__ seg_start,
    const float* __restrict__ emb, const float* __restrict__ W,
    __half* __restrict__ embw, int T, int B, int V, int mtiles, int nTrans) {
  if ((int)blockIdx.x >= nTrans) {
    // ---- boundaries: seg_start[s] = lower_bound(segs, s), streaming ----
    const int i = (blockIdx.x - nTrans) * 256 + threadIdx.x;
    if (i > T) return;
    const int cur = (i < T) ? segs[i] : B;
    const int prev = (i > 0) ? segs[i - 1] : -1;
    for (int s = prev + 1; s <= cur; ++s) seg_start[s] = i;
    return;
  }

  // ---- table transform ----
  const int wid = blockIdx.x * 4 + (threadIdx.x >> 6);
  const int nwaves = nTrans * 4;
  const int lane = threadIdx.x & 63;
  const int lr = lane & 15;   // A-row / B-col / D-col
  const int lg = lane >> 4;   // k-group (A/B), row-group (D)

  // Preload all B fragments of W (fp32 -> fp16). W is 64KB, L1/L2-hot.
  f16x8 bfrag[8][4];
#pragma unroll
  for (int n = 0; n < 8; ++n)
#pragma unroll
    for (int s = 0; s < 4; ++s) {
      const float* wp = W + (size_t)(s * 32 + lg * 8) * DIM + n * 16 + lr;
      f16x8 f;
#pragma unroll
      for (int i = 0; i < 8; ++i) f[i] = (_Float16)wp[(size_t)i * DIM];
      bfrag[n][s] = f;
    }

  for (int mt = wid; mt < mtiles; mt += nwaves) {
    const float* arow = emb + (size_t)(mt * 16 + lr) * DIM;
    f16x8 afrag[4];
#pragma unroll
    for (int s = 0; s < 4; ++s) {
      const float4 a0 = *reinterpret_cast<const float4*>(arow + s * 32 + lg * 8);
      const float4 a1 = *reinterpret_cast<const float4*>(arow + s * 32 + lg * 8 + 4);
      f16x8 f;
      f[0] = (_Float16)a0.x; f[1] = (_Float16)a0.y;
      f[2] = (_Float16)a0.z; f[3] = (_Float16)a0.w;
      f[4] = (_Float16)a1.x; f[5] = (_Float16)a1.y;
      f[6] = (_Float16)a1.z; f[7] = (_Float16)a1.w;
      afrag[s] = f;
    }
#pragma unroll
    for (int n = 0; n < 8; ++n) {
      f32x4 acc = {0.f, 0.f, 0.f, 0.f};
#pragma unroll
      for (int s = 0; s < 4; ++s)
        acc = __builtin_amdgcn_mfma_f32_16x16x32_f16(afrag[s], bfrag[n][s],
                                                     acc, 0, 0, 0);
#pragma unroll
      for (int j = 0; j < 4; ++j)
        embw[(size_t)(mt * 16 + lg * 4 + j) * DIM + n * 16 + lr] =
            __float2half(acc[j]);
    }
  }

  // tail rows if V % 16 != 0 (dead for V=100000, kept for safety)
  const int tailStart = mtiles * 16;
  if (wid == 0 && tailStart < V) {
    const int c2 = lane * 2;
    for (int r = tailStart; r < V; ++r) {
      float s0 = 0.f, s1 = 0.f;
      for (int k = 0; k < DIM; ++k) {
        const float e = emb[(size_t)r * DIM + k];
        s0 = fmaf(e, W[(size_t)k * DIM + c2], s0);
        s1 = fmaf(e, W[(size_t)k * DIM + c2 + 1], s1);
      }
      embw[(size_t)r * DIM + c2] = __float2half(s0);
      embw[(size_t)r * DIM + c2 + 1] = __float2half(s1);
    }
  }
}

// ---------- Kernel 2: gather + segment sum over embW, + bias + relu -------
// One wave per segment (4 waves/block). Per 16-row batch: 8 independent
// 8B-per-lane loads in flight (2 rows per wave-load: lanes 0-31 = even row,
// lanes 32-63 = odd row; 4 fp16 cols per lane). Since the table is already
// transformed by W, the epilogue is just +bias, relu, store -> out.

#define ADDE(u)                                                            \
  {                                                                        \
    const __half2 h0 = *reinterpret_cast<const __half2*>(&r##u.x);         \
    const __half2 h1 = *reinterpret_cast<const __half2*>(&r##u.y);         \
    const float2 f0 = __half22float2(h0);                                  \
    const float2 f1 = __half22float2(h1);                                  \
    acc.x += f0.x; acc.y += f0.y; acc.z += f1.x; acc.w += f1.y;            \
  }
#define LOADE(u, TIDX)                                                     \
  const int t##u = tokens[(TIDX)];                                         \
  const uint2 r##u = *reinterpret_cast<const uint2*>(                      \
      embh + (size_t)t##u * DIM + c4);

__global__ __launch_bounds__(256, 4) void segsum_out_f16(
    const int* __restrict__ tokens, const __half* __restrict__ embh,
    const int* __restrict__ seg_start, const float* __restrict__ bias,
    float* __restrict__ out, int B) {
  const int seg = blockIdx.x * 4 + (threadIdx.x >> 6);
  if (seg >= B) return;
  const int lane = threadIdx.x & 63;
  const int half = lane >> 5;
  const int c4 = (lane & 31) * 4;
  const int lo = seg_start[seg], hi = seg_start[seg + 1];
  const int cnt = hi - lo;
  float4 acc = make_float4(0.f, 0.f, 0.f, 0.f);

  int base = lo;
  const int nb = cnt >> 4;
  for (int b = 0; b < nb; ++b, base += 16) {
    LOADE(0, base + 0 + half)  LOADE(1, base + 2 + half)
    LOADE(2, base + 4 + half)  LOADE(3, base + 6 + half)
    LOADE(4, base + 8 + half)  LOADE(5, base + 10 + half)
    LOADE(6, base + 12 + half) LOADE(7, base + 14 + half)
    ADDE(0) ADDE(1) ADDE(2) ADDE(3) ADDE(4) ADDE(5) ADDE(6) ADDE(7)
  }
  if (cnt & 15) {
    const int last = hi - 1;
#define LOADT(u) const int i##u = base + 2 * u + half; LOADE(u, min(i##u, last))
    LOADT(0) LOADT(1) LOADT(2) LOADT(3)
    LOADT(4) LOADT(5) LOADT(6) LOADT(7)
    if (i0 <= last) ADDE(0)
    if (i1 <= last) ADDE(1)
    if (i2 <= last) ADDE(2)
    if (i3 <= last) ADDE(3)
    if (i4 <= last) ADDE(4)
    if (i5 <= last) ADDE(5)
    if (i6 <= last) ADDE(6)
    if (i7 <= last) ADDE(7)
#undef LOADT
  }
  acc.x += __shfl_xor(acc.x, 32);
  acc.y += __shfl_xor(acc.y, 32);
  acc.z += __shfl_xor(acc.z, 32);
  acc.w += __shfl_xor(acc.w, 32);
  if (half == 0) {
    const float4 bv = *reinterpret_cast<const float4*>(bias + c4);
    float4 o;
    o.x = fmaxf(acc.x + bv.x, 0.f);
    o.y = fmaxf(acc.y + bv.y, 0.f);
    o.z = fmaxf(acc.z + bv.z, 0.f);
    o.w = fmaxf(acc.w + bv.w, 0.f);
    *reinterpret_cast<float4*>(out + (size_t)seg * DIM + c4) = o;
  }
}

// =================== fp32 fallback path (ws too small) ====================
__global__ __launch_bounds__(256) void boundaries_kernel(
    const int* __restrict__ segs, int* __restrict__ seg_start, int T, int B) {
  const int i = blockIdx.x * 256 + threadIdx.x;
  if (i > T) return;
  const int cur = (i < T) ? segs[i] : B;
  const int prev = (i > 0) ? segs[i - 1] : -1;
  for (int s = prev + 1; s <= cur; ++s) seg_start[s] = i;
}

#define LOADF(u, TIDX)                                                     \
  const int t##u = tokens[(TIDX)];                                         \
  const float4 e##u = *reinterpret_cast<const float4*>(                    \
      emb + (size_t)t##u * DIM + c4);
#define ADDF(u) { acc.x += e##u.x; acc.y += e##u.y; acc.z += e##u.z; acc.w += e##u.w; }

__global__ __launch_bounds__(256, 4) void segsum_f32(
    const int* __restrict__ tokens, const float* __restrict__ emb,
    const int* __restrict__ seg_start, float* __restrict__ bow, int B) {
  const int seg = blockIdx.x * 4 + (threadIdx.x >> 6);
  if (seg >= B) return;
  const int lane = threadIdx.x & 63;
  const int half = lane >> 5;
  const int c4 = (lane & 31) * 4;
  const int lo = seg_start[seg], hi = seg_start[seg + 1];
  const int cnt = hi - lo;
  float4 acc = make_float4(0.f, 0.f, 0.f, 0.f);

  int base = lo;
  const int nb = cnt >> 4;
  for (int b = 0; b < nb; ++b, base += 16) {
    LOADF(0, base + 0 + half)  LOADF(1, base + 2 + half)
    LOADF(2, base + 4 + half)  LOADF(3, base + 6 + half)
    LOADF(4, base + 8 + half)  LOADF(5, base + 10 + half)
    LOADF(6, base + 12 + half) LOADF(7, base + 14 + half)
    ADDF(0) ADDF(1) ADDF(2) ADDF(3) ADDF(4) ADDF(5) ADDF(6) ADDF(7)
  }
  if (cnt & 15) {
    const int last = hi - 1;
#define LOADT(u) const int i##u = base + 2 * u + half; LOADF(u, min(i##u, last))
    LOADT(0) LOADT(1) LOADT(2) LOADT(3)
    LOADT(4) LOADT(5) LOADT(6) LOADT(7)
    if (i0 <= last) ADDF(0)
    if (i1 <= last) ADDF(1)
    if (i2 <= last) ADDF(2)
    if (i3 <= last) ADDF(3)
    if (i4 <= last) ADDF(4)
    if (i5 <= last) ADDF(5)
    if (i6 <= last) ADDF(6)
    if (i7 <= last) ADDF(7)
#undef LOADT
  }
  acc.x += __shfl_xor(acc.x, 32);
  acc.y += __shfl_xor(acc.y, 32);
  acc.z += __shfl_xor(acc.z, 32);
  acc.w += __shfl_xor(acc.w, 32);
  if (half == 0)
    *reinterpret_cast<float4*>(bow + (size_t)seg * DIM + c4) = acc;
}

// out = relu(bow @ W + b), in-place over d_out (fallback only)
__global__ __launch_bounds__(256) void gemm_bias_relu(
    const float* __restrict__ bow, const float* __restrict__ W,
    const float* __restrict__ bias, float* __restrict__ out) {
  __shared__ float bt[GROWS][DIM];
  const int tid = threadIdx.x;
  const size_t row0 = (size_t)blockIdx.x * GROWS;

  {
    const float4* src = reinterpret_cast<const float4*>(bow + row0 * DIM);
    float4* dst = reinterpret_cast<float4*>(&bt[0][0]);
#pragma unroll
    for (int i = 0; i < (GROWS * DIM / 4) / 256; ++i)
      dst[tid + 256 * i] = src[tid + 256 * i];
  }
  __syncthreads();

  const int cg = tid & 31;
  const int rg = tid >> 5;
  const int c0 = cg * 4;

  float acc[4][4] = {};
#pragma unroll 4
  for (int k = 0; k < DIM; ++k) {
    const float4 w4 = *reinterpret_cast<const float4*>(W + (size_t)k * DIM + c0);
#pragma unroll
    for (int j = 0; j < 4; ++j) {
      const float s = bt[rg * 4 + j][k];
      acc[j][0] = fmaf(s, w4.x, acc[j][0]);
      acc[j][1] = fmaf(s, w4.y, acc[j][1]);
      acc[j][2] = fmaf(s, w4.z, acc[j][2]);
      acc[j][3] = fmaf(s, w4.w, acc[j][3]);
    }
  }

  const float4 bv = *reinterpret_cast<const float4*>(bias + c0);
#pragma unroll
  for (int j = 0; j < 4; ++j) {
    float4 o;
    o.x = fmaxf(acc[j][0] + bv.x, 0.f);
    o.y = fmaxf(acc[j][1] + bv.y, 0.f);
    o.z = fmaxf(acc[j][2] + bv.z, 0.f);
    o.w = fmaxf(acc[j][3] + bv.w, 0.f);
    *reinterpret_cast<float4*>(out + (row0 + rg * 4 + j) * DIM + c0) = o;
  }
}

extern "C" void kernel_launch(void* const* d_in, const int* in_sizes, int n_in,
                              void* d_out, int out_size, void* d_ws, size_t ws_size,
                              hipStream_t stream) {
  const int* tokens = (const int*)d_in[0];
  const int* segs = (const int*)d_in[1];
  const float* emb = (const float*)d_in[2];
  const float* W = (const float*)d_in[3];
  const float* bias = (const float*)d_in[4];
  float* out = (float*)d_out;

  const int T = in_sizes[0];
  const int B = out_size / DIM;       // 16384
  const int V = in_sizes[2] / DIM;    // 100000

  int* seg_start = (int*)d_ws;                       // (B+1) ints
  const size_t ss_bytes = ((size_t)(B + 1) * 4 + 255) & ~(size_t)255;

  const bool f16ok = ws_size >= ss_bytes + (size_t)V * DIM * 2;
  if (f16ok) {
    __half* embw = (__half*)((char*)d_ws + ss_bytes);
    const int nbBound = (T + 1 + 255) / 256;
    const int NTRANS = 512;                          // transform blocks
    const int mtiles = V / 16;
    prep_kernel<<<NTRANS + nbBound, 256, 0, stream>>>(
        segs, seg_start, emb, W, embw, T, B, V, mtiles, NTRANS);
    segsum_out_f16<<<(B + 3) / 4, 256, 0, stream>>>(
        tokens, embw, seg_start, bias, out, B);
  } else {
    float* bow = out;                                // in-place: gather -> GEMM
    boundaries_kernel<<<(T + 1 + 255) / 256, 256, 0, stream>>>(segs, seg_start, T, B);
    segsum_f32<<<(B + 3) / 4, 256, 0, stream>>>(tokens, emb, seg_start, bow, B);
    gemm_bias_relu<<<B / GROWS, 256, 0, stream>>>(bow, W, bias, out);
  }
}

// Round 2
// 48.252 us; speedup vs baseline: 1.3817x; 1.1391x over previous
//
#include <hip/hip_runtime.h>
#include <hip/hip_fp16.h>

#define DIM 128
#define GROWS 32

typedef _Float16 f16x8 __attribute__((ext_vector_type(8)));
typedef float f32x4 __attribute__((ext_vector_type(4)));

// ---------- Kernel 1 (fused): qtab = int8_rowquant(emb @ W), scales[r] =
// rowmax/127, via fp16 MFMA (memory-bound; GEMM rides free on the matrix
// pipe) + segment-boundary scan in the same launch.
//
// MFMA fragment layouts (mfma_f32_16x16x32_f16, harness-verified round 1):
//   A (16x32): row = lane&15, k = (lane>>4)*8 + i  -> 8 contiguous floats
//   B (32x16): col = lane&15, k = (lane>>4)*8 + i  -> stride-DIM scalars
//   D (16x16): col = lane&15, row = (lane>>4)*4 + reg
__global__ __launch_bounds__(256, 2) void prep_kernel(
    const int* __restrict__ segs, int* __restrict__ seg_start,
    const float* __restrict__ emb, const float* __restrict__ W,
    signed char* __restrict__ qtab, float* __restrict__ scales,
    int T, int B, int V, int mtiles, int nTrans) {
  if ((int)blockIdx.x >= nTrans) {
    // ---- boundaries: seg_start[s] = lower_bound(segs, s), streaming ----
    const int i = (blockIdx.x - nTrans) * 256 + threadIdx.x;
    if (i > T) return;
    const int cur = (i < T) ? segs[i] : B;
    const int prev = (i > 0) ? segs[i - 1] : -1;
    for (int s = prev + 1; s <= cur; ++s) seg_start[s] = i;
    return;
  }

  const int wid = blockIdx.x * 4 + (threadIdx.x >> 6);
  const int nwaves = nTrans * 4;
  const int lane = threadIdx.x & 63;
  const int lr = lane & 15;   // A-row / B-col / D-col
  const int lg = lane >> 4;   // k-group (A/B), row-group (D)

  // Preload all B fragments of W (fp32 -> fp16). W is 64KB, L1/L2-hot.
  f16x8 bfrag[8][4];
#pragma unroll
  for (int n = 0; n < 8; ++n)
#pragma unroll
    for (int s = 0; s < 4; ++s) {
      const float* wp = W + (size_t)(s * 32 + lg * 8) * DIM + n * 16 + lr;
      f16x8 f;
#pragma unroll
      for (int i = 0; i < 8; ++i) f[i] = (_Float16)wp[(size_t)i * DIM];
      bfrag[n][s] = f;
    }

  for (int mt = wid; mt < mtiles; mt += nwaves) {
    const float* arow = emb + (size_t)(mt * 16 + lr) * DIM;
    f16x8 afrag[4];
#pragma unroll
    for (int s = 0; s < 4; ++s) {
      const float4 a0 = *reinterpret_cast<const float4*>(arow + s * 32 + lg * 8);
      const float4 a1 = *reinterpret_cast<const float4*>(arow + s * 32 + lg * 8 + 4);
      f16x8 f;
      f[0] = (_Float16)a0.x; f[1] = (_Float16)a0.y;
      f[2] = (_Float16)a0.z; f[3] = (_Float16)a0.w;
      f[4] = (_Float16)a1.x; f[5] = (_Float16)a1.y;
      f[6] = (_Float16)a1.z; f[7] = (_Float16)a1.w;
      afrag[s] = f;
    }
    f32x4 accs[8];
#pragma unroll
    for (int n = 0; n < 8; ++n) {
      f32x4 a = {0.f, 0.f, 0.f, 0.f};
#pragma unroll
      for (int s = 0; s < 4; ++s)
        a = __builtin_amdgcn_mfma_f32_16x16x32_f16(afrag[s], bfrag[n][s],
                                                   a, 0, 0, 0);
      accs[n] = a;
    }
    // per-row absmax: in-lane over n, then across the 16 lr lanes
    const int r0 = mt * 16 + lg * 4;
    float inv[4];
#pragma unroll
    for (int j = 0; j < 4; ++j) {
      float mm = fabsf(accs[0][j]);
#pragma unroll
      for (int n = 1; n < 8; ++n) mm = fmaxf(mm, fabsf(accs[n][j]));
      mm = fmaxf(mm, __shfl_xor(mm, 1));
      mm = fmaxf(mm, __shfl_xor(mm, 2));
      mm = fmaxf(mm, __shfl_xor(mm, 4));
      mm = fmaxf(mm, __shfl_xor(mm, 8));
      inv[j] = (mm > 0.f) ? 127.f / mm : 0.f;
      if (lr == 0) scales[r0 + j] = mm * (1.f / 127.f);
    }
#pragma unroll
    for (int n = 0; n < 8; ++n)
#pragma unroll
      for (int j = 0; j < 4; ++j)
        qtab[(size_t)(r0 + j) * DIM + n * 16 + lr] =
            (signed char)(int)rintf(accs[n][j] * inv[j]);
  }

  // tail rows if V % 16 != 0 (dead for V=100000, kept for safety)
  const int tailStart = mtiles * 16;
  if (wid == 0 && tailStart < V) {
    const int c2 = lane * 2;
    for (int r = tailStart; r < V; ++r) {
      float s0 = 0.f, s1 = 0.f;
      for (int k = 0; k < DIM; ++k) {
        const float e = emb[(size_t)r * DIM + k];
        s0 = fmaf(e, W[(size_t)k * DIM + c2], s0);
        s1 = fmaf(e, W[(size_t)k * DIM + c2 + 1], s1);
      }
      float mm = fmaxf(fabsf(s0), fabsf(s1));
      mm = fmaxf(mm, __shfl_xor(mm, 1));
      mm = fmaxf(mm, __shfl_xor(mm, 2));
      mm = fmaxf(mm, __shfl_xor(mm, 4));
      mm = fmaxf(mm, __shfl_xor(mm, 8));
      mm = fmaxf(mm, __shfl_xor(mm, 16));
      mm = fmaxf(mm, __shfl_xor(mm, 32));
      const float iv = (mm > 0.f) ? 127.f / mm : 0.f;
      if (lane == 0) scales[r] = mm * (1.f / 127.f);
      qtab[(size_t)r * DIM + c2] = (signed char)(int)rintf(s0 * iv);
      qtab[(size_t)r * DIM + c2 + 1] = (signed char)(int)rintf(s1 * iv);
    }
  }
}

// ---------- Kernel 2: int8 gather + segment sum + bias + relu -------------
// One wave per segment. 32-row batches: 8 uint2 loads in flight, each load
// = 4 rows (16 lanes x 8B = one 128B row). Lane's 8 bytes are cols
// (lane&15)*8 .. +7 of its group's row; per-row fp32 scale folded into the
// 8 fma-accumulates. Cross-group reduce via shfl_xor(16|32); lanes 0-15
// apply bias+relu and write the 512B output row.

#define ACCB(W_, SH, AI, SV) \
  acc[AI] = fmaf(SV, (float)((int)((W_) << (SH)) >> 24), acc[AI]);
#define ADDQ(u, SV) {                                                      \
  ACCB(r##u.x, 24, 0, SV) ACCB(r##u.x, 16, 1, SV)                          \
  ACCB(r##u.x,  8, 2, SV) ACCB(r##u.x,  0, 3, SV)                          \
  ACCB(r##u.y, 24, 4, SV) ACCB(r##u.y, 16, 5, SV)                          \
  ACCB(r##u.y,  8, 6, SV) ACCB(r##u.y,  0, 7, SV) }
#define LOADQ(u, TIDX)                                                     \
  const int t##u = tokens[(TIDX)];                                         \
  const float s##u = scales[t##u];                                         \
  const uint2 r##u = *reinterpret_cast<const uint2*>(                      \
      qtab + (size_t)t##u * DIM + c8);

__global__ __launch_bounds__(256, 6) void segsum_q8(
    const int* __restrict__ tokens, const signed char* __restrict__ qtab,
    const float* __restrict__ scales, const int* __restrict__ seg_start,
    const float* __restrict__ bias, float* __restrict__ out, int B) {
  const int seg = blockIdx.x * 4 + (threadIdx.x >> 6);
  if (seg >= B) return;
  const int lane = threadIdx.x & 63;
  const int g = lane >> 4;
  const int c8 = (lane & 15) * 8;
  const int lo = seg_start[seg], hi = seg_start[seg + 1];
  const int cnt = hi - lo;
  float acc[8] = {0.f, 0.f, 0.f, 0.f, 0.f, 0.f, 0.f, 0.f};

  int base = lo;
  const int nb = cnt >> 5;
  for (int b = 0; b < nb; ++b, base += 32) {
    LOADQ(0, base + 0 + g)  LOADQ(1, base + 4 + g)
    LOADQ(2, base + 8 + g)  LOADQ(3, base + 12 + g)
    LOADQ(4, base + 16 + g) LOADQ(5, base + 20 + g)
    LOADQ(6, base + 24 + g) LOADQ(7, base + 28 + g)
    ADDQ(0, s0) ADDQ(1, s1) ADDQ(2, s2) ADDQ(3, s3)
    ADDQ(4, s4) ADDQ(5, s5) ADDQ(6, s6) ADDQ(7, s7)
  }
  if (cnt & 31) {
    const int last = hi - 1;
#define LQT(u)                                                             \
  const int i##u = base + 4 * u + g;                                       \
  const int t##u = tokens[min(i##u, last)];                                \
  const float s##u = (i##u <= last) ? scales[t##u] : 0.f;                  \
  const uint2 r##u = *reinterpret_cast<const uint2*>(                      \
      qtab + (size_t)t##u * DIM + c8);
    LQT(0) LQT(1) LQT(2) LQT(3) LQT(4) LQT(5) LQT(6) LQT(7)
    ADDQ(0, s0) ADDQ(1, s1) ADDQ(2, s2) ADDQ(3, s3)
    ADDQ(4, s4) ADDQ(5, s5) ADDQ(6, s6) ADDQ(7, s7)
#undef LQT
  }
#pragma unroll
  for (int i = 0; i < 8; ++i) {
    acc[i] += __shfl_xor(acc[i], 16);
    acc[i] += __shfl_xor(acc[i], 32);
  }
  if (g == 0) {
    const float4 b0 = *reinterpret_cast<const float4*>(bias + c8);
    const float4 b1 = *reinterpret_cast<const float4*>(bias + c8 + 4);
    float4 o0, o1;
    o0.x = fmaxf(acc[0] + b0.x, 0.f);
    o0.y = fmaxf(acc[1] + b0.y, 0.f);
    o0.z = fmaxf(acc[2] + b0.z, 0.f);
    o0.w = fmaxf(acc[3] + b0.w, 0.f);
    o1.x = fmaxf(acc[4] + b1.x, 0.f);
    o1.y = fmaxf(acc[5] + b1.y, 0.f);
    o1.z = fmaxf(acc[6] + b1.z, 0.f);
    o1.w = fmaxf(acc[7] + b1.w, 0.f);
    *reinterpret_cast<float4*>(out + (size_t)seg * DIM + c8) = o0;
    *reinterpret_cast<float4*>(out + (size_t)seg * DIM + c8 + 4) = o1;
  }
}

// =================== fp32 fallback path (ws too small) ====================
__global__ __launch_bounds__(256) void boundaries_kernel(
    const int* __restrict__ segs, int* __restrict__ seg_start, int T, int B) {
  const int i = blockIdx.x * 256 + threadIdx.x;
  if (i > T) return;
  const int cur = (i < T) ? segs[i] : B;
  const int prev = (i > 0) ? segs[i - 1] : -1;
  for (int s = prev + 1; s <= cur; ++s) seg_start[s] = i;
}

#define LOADF(u, TIDX)                                                     \
  const int t##u = tokens[(TIDX)];                                         \
  const float4 e##u = *reinterpret_cast<const float4*>(                    \
      emb + (size_t)t##u * DIM + c4);
#define ADDF(u) { acc.x += e##u.x; acc.y += e##u.y; acc.z += e##u.z; acc.w += e##u.w; }

__global__ __launch_bounds__(256, 4) void segsum_f32(
    const int* __restrict__ tokens, const float* __restrict__ emb,
    const int* __restrict__ seg_start, float* __restrict__ bow, int B) {
  const int seg = blockIdx.x * 4 + (threadIdx.x >> 6);
  if (seg >= B) return;
  const int lane = threadIdx.x & 63;
  const int half = lane >> 5;
  const int c4 = (lane & 31) * 4;
  const int lo = seg_start[seg], hi = seg_start[seg + 1];
  const int cnt = hi - lo;
  float4 acc = make_float4(0.f, 0.f, 0.f, 0.f);

  int base = lo;
  const int nb = cnt >> 4;
  for (int b = 0; b < nb; ++b, base += 16) {
    LOADF(0, base + 0 + half)  LOADF(1, base + 2 + half)
    LOADF(2, base + 4 + half)  LOADF(3, base + 6 + half)
    LOADF(4, base + 8 + half)  LOADF(5, base + 10 + half)
    LOADF(6, base + 12 + half) LOADF(7, base + 14 + half)
    ADDF(0) ADDF(1) ADDF(2) ADDF(3) ADDF(4) ADDF(5) ADDF(6) ADDF(7)
  }
  if (cnt & 15) {
    const int last = hi - 1;
#define LOADT(u) const int i##u = base + 2 * u + half; LOADF(u, min(i##u, last))
    LOADT(0) LOADT(1) LOADT(2) LOADT(3)
    LOADT(4) LOADT(5) LOADT(6) LOADT(7)
    if (i0 <= last) ADDF(0)
    if (i1 <= last) ADDF(1)
    if (i2 <= last) ADDF(2)
    if (i3 <= last) ADDF(3)
    if (i4 <= last) ADDF(4)
    if (i5 <= last) ADDF(5)
    if (i6 <= last) ADDF(6)
    if (i7 <= last) ADDF(7)
#undef LOADT
  }
  acc.x += __shfl_xor(acc.x, 32);
  acc.y += __shfl_xor(acc.y, 32);
  acc.z += __shfl_xor(acc.z, 32);
  acc.w += __shfl_xor(acc.w, 32);
  if (half == 0)
    *reinterpret_cast<float4*>(bow + (size_t)seg * DIM + c4) = acc;
}

// out = relu(bow @ W + b), in-place over d_out (fallback only)
__global__ __launch_bounds__(256) void gemm_bias_relu(
    const float* __restrict__ bow, const float* __restrict__ W,
    const float* __restrict__ bias, float* __restrict__ out) {
  __shared__ float bt[GROWS][DIM];
  const int tid = threadIdx.x;
  const size_t row0 = (size_t)blockIdx.x * GROWS;

  {
    const float4* src = reinterpret_cast<const float4*>(bow + row0 * DIM);
    float4* dst = reinterpret_cast<float4*>(&bt[0][0]);
#pragma unroll
    for (int i = 0; i < (GROWS * DIM / 4) / 256; ++i)
      dst[tid + 256 * i] = src[tid + 256 * i];
  }
  __syncthreads();

  const int cg = tid & 31;
  const int rg = tid >> 5;
  const int c0 = cg * 4;

  float acc[4][4] = {};
#pragma unroll 4
  for (int k = 0; k < DIM; ++k) {
    const float4 w4 = *reinterpret_cast<const float4*>(W + (size_t)k * DIM + c0);
#pragma unroll
    for (int j = 0; j < 4; ++j) {
      const float s = bt[rg * 4 + j][k];
      acc[j][0] = fmaf(s, w4.x, acc[j][0]);
      acc[j][1] = fmaf(s, w4.y, acc[j][1]);
      acc[j][2] = fmaf(s, w4.z, acc[j][2]);
      acc[j][3] = fmaf(s, w4.w, acc[j][3]);
    }
  }

  const float4 bv = *reinterpret_cast<const float4*>(bias + c0);
#pragma unroll
  for (int j = 0; j < 4; ++j) {
    float4 o;
    o.x = fmaxf(acc[j][0] + bv.x, 0.f);
    o.y = fmaxf(acc[j][1] + bv.y, 0.f);
    o.z = fmaxf(acc[j][2] + bv.z, 0.f);
    o.w = fmaxf(acc[j][3] + bv.w, 0.f);
    *reinterpret_cast<float4*>(out + (row0 + rg * 4 + j) * DIM + c0) = o;
  }
}

extern "C" void kernel_launch(void* const* d_in, const int* in_sizes, int n_in,
                              void* d_out, int out_size, void* d_ws, size_t ws_size,
                              hipStream_t stream) {
  const int* tokens = (const int*)d_in[0];
  const int* segs = (const int*)d_in[1];
  const float* emb = (const float*)d_in[2];
  const float* W = (const float*)d_in[3];
  const float* bias = (const float*)d_in[4];
  float* out = (float*)d_out;

  const int T = in_sizes[0];
  const int B = out_size / DIM;       // 16384
  const int V = in_sizes[2] / DIM;    // 100000

  int* seg_start = (int*)d_ws;                       // (B+1) ints
  const size_t ss_bytes = ((size_t)(B + 1) * 4 + 255) & ~(size_t)255;
  const size_t sc_bytes = ((size_t)V * 4 + 255) & ~(size_t)255;

  const bool qok = ws_size >= ss_bytes + sc_bytes + (size_t)V * DIM;
  if (qok) {
    float* scales = (float*)((char*)d_ws + ss_bytes);
    signed char* qtab = (signed char*)((char*)d_ws + ss_bytes + sc_bytes);
    const int nbBound = (T + 1 + 255) / 256;
    const int NTRANS = 512;                          // transform blocks
    const int mtiles = V / 16;
    prep_kernel<<<NTRANS + nbBound, 256, 0, stream>>>(
        segs, seg_start, emb, W, qtab, scales, T, B, V, mtiles, NTRANS);
    segsum_q8<<<(B + 3) / 4, 256, 0, stream>>>(
        tokens, qtab, scales, seg_start, bias, out, B);
  } else {
    float* bow = out;                                // in-place: gather -> GEMM
    boundaries_kernel<<<(T + 1 + 255) / 256, 256, 0, stream>>>(segs, seg_start, T, B);
    segsum_f32<<<(B + 3) / 4, 256, 0, stream>>>(tokens, emb, seg_start, bow, B);
    gemm_bias_relu<<<B / GROWS, 256, 0, stream>>>(bow, W, bias, out);
  }
}